// Round 9
// baseline (591.054 us; speedup 1.0000x reference)
//
#include <hip/hip_runtime.h>
#include <stdint.h>

// PAM_Module: B=8, C=512, H=W=64 -> N=4096, O=64. Dtype auto-detected (bf16 vs fp32).
// out = gamma * (vw @ (xf @ att^T) + vb) + x   (softmax rows sum to 1 => vb passes through)
// MFMA pipeline:
//   K0 detect, K1 prep (wt/bcat/vbf/gf fp32 + vw->bf16 vwb),
//   K2 proj -> Qb,Kb bf16 [b][n][64] (fp32 path also writes xbf; bf16 aliases x),
//   K3 attn_mfma: single-pass shifted-exp softmax + PV + fused vw-GEMM epilogue.
//
// R9 (latency-exposure fix): R6==R8 null showed the limiter scales with work, all
// pipes ~20% -- exposed VMEM latency on the small af load batches (reg budget caps
// batches at 4 loads; each pays ~300cyc L2 latency uncovered). Changes:
//  1. p_compute in h-PAIRS (sv[2] live, exp immediately) -> frees ~8 VGPR.
//  2. hoist pv's FIRST af batch to right after the barrier, before p_compute:
//     its latency hides under p_compute's MFMA+exp instead of stalling pv.
// Keeps R8 shape: 64-i blocks, 512 thr, j-tile 128, acc[4][4] (64 AGPR),
// __launch_bounds__(512,4) -> 2 blocks/CU, XCD-pinned batches, depth-2 pipeline.
// ws: flag@0 gf@16 bcat@32 vbf@544 wt@2592 Qb@264736 Kb@4459040 vwb@8653344
//     xbf@9177632  (total 42,732,064 B)

#define B_ 8
#define C_ 512
#define N_ 4096

typedef unsigned short u16;
typedef unsigned int u32;
typedef __attribute__((ext_vector_type(8))) short bf16x8;
typedef __attribute__((ext_vector_type(4))) float f32x4;

static __device__ __forceinline__ float b2f(u16 u) {
    return __uint_as_float(((u32)u) << 16);
}
static __device__ __forceinline__ u16 f2b(float f) {
    u32 u = __float_as_uint(f);
    u = u + 0x7fffu + ((u >> 16) & 1u);   // RNE
    return (u16)(u >> 16);
}
static __device__ __forceinline__ float ldf(const void* p, size_t i, int fl) {
    return fl ? b2f(((const u16*)p)[i]) : ((const float*)p)[i];
}

// ---------------- kernel 0: dtype detector ----------------------------------------
__global__ void detect_dtype(const u16* __restrict__ x, int* __restrict__ flag) {
    __shared__ int cnt[256];
    int t = threadIdx.x;
    int c = 0;
    for (int i = t; i < 4096; i += 256) {
        int e = (x[i] >> 7) & 0xFF;
        if (e >= 95 && e <= 140) c++;
    }
    cnt[t] = c;
    __syncthreads();
    for (int s = 128; s > 0; s >>= 1) {
        if (t < s) cnt[t] += cnt[t + s];
        __syncthreads();
    }
    if (t == 0) *flag = (cnt[0] >= 3686) ? 1 : 0;   // 1 = bf16, 0 = fp32
}

// ---------------- kernel 1: params -> fp32 ws, vw -> bf16 --------------------------
__global__ void prep_params(const void* __restrict__ qw, const void* __restrict__ qb,
                            const void* __restrict__ kw, const void* __restrict__ kb,
                            const void* __restrict__ vb, const void* __restrict__ gm,
                            const void* __restrict__ vw, const int* __restrict__ flagp,
                            float* __restrict__ wt, float* __restrict__ bcat,
                            float* __restrict__ vbf, float* __restrict__ gf,
                            u16* __restrict__ vwb) {
    int fl = *flagp;
    int gid = blockIdx.x * 256 + threadIdx.x;   // grid 256*256 = 65536
    if (gid < C_ * 128) {
        int c = gid >> 7, o = gid & 127;
        wt[c * 128 + o] = (o < 64) ? ldf(qw, (size_t)o * C_ + c, fl)
                                   : ldf(kw, (size_t)(o - 64) * C_ + c, fl);
    }
    if (gid < 128) bcat[gid] = (gid < 64) ? ldf(qb, gid, fl) : ldf(kb, gid - 64, fl);
    if (gid < C_) vbf[gid] = ldf(vb, gid, fl);
    if (gid == 0) gf[0] = ldf(gm, 0, fl);
    {   // vw -> bf16: 65536 threads x 4 elems = 262144 = C*C
        int v0 = gid * 4;
        ushort4 h;
        h.x = f2b(ldf(vw, v0 + 0, fl));
        h.y = f2b(ldf(vw, v0 + 1, fl));
        h.z = f2b(ldf(vw, v0 + 2, fl));
        h.w = f2b(ldf(vw, v0 + 3, fl));
        *(ushort4*)(vwb + v0) = h;
    }
}

// ---------------- kernel 2: Q/K projection -> bf16, grid (2, 64, 8) ---------------
// fp32 input: og==0 blocks also emit x as bf16 into xbf (fused xconv).
__global__ __launch_bounds__(256) void proj_qk(
        const void* __restrict__ xin, const int* __restrict__ flagp,
        const float* __restrict__ wt, const float* __restrict__ bcat,
        u16* __restrict__ Qb, u16* __restrict__ Kb, u16* __restrict__ xbf) {
    __shared__ __align__(16) char smem[32768];
    float* xs  = (float*)smem;            // [64][64]
    float* wsh = (float*)(smem + 16384);  // [64][64]
    const u16*   xb = (const u16*)xin;
    const float* xf = (const float*)xin;
    int fl = *flagp;

    int t = threadIdx.x;
    int og = blockIdx.x;
    int n0 = blockIdx.y * 64;
    int b  = blockIdx.z;
    int oc0 = og * 64;
    int tn = t & 15, to = t >> 4;

    float acc[4][4];
#pragma unroll
    for (int i = 0; i < 4; ++i)
#pragma unroll
        for (int j = 0; j < 4; ++j) acc[i][j] = 0.f;

    for (int c0 = 0; c0 < C_; c0 += 64) {
        __syncthreads();
        if (fl) {
#pragma unroll
            for (int rep = 0; rep < 4; ++rep) {
                int idx4 = rep * 256 + t;
                int cc = idx4 >> 4;
                int nn4 = (idx4 & 15) << 2;
                ushort4 uv = *(const ushort4*)(xb + ((size_t)(b * C_ + c0 + cc)) * N_ + n0 + nn4);
                float4 f;
                f.x = b2f(uv.x); f.y = b2f(uv.y); f.z = b2f(uv.z); f.w = b2f(uv.w);
                *(float4*)(xs + cc * 64 + nn4) = f;
            }
        } else {
#pragma unroll
            for (int rep = 0; rep < 4; ++rep) {
                int idx4 = rep * 256 + t;
                int cc = idx4 >> 4;
                int nn4 = (idx4 & 15) << 2;
                float4 v = *(const float4*)(xf + ((size_t)(b * C_ + c0 + cc)) * N_ + n0 + nn4);
                *(float4*)(xs + cc * 64 + nn4) = v;
                if (og == 0) {   // fused x -> bf16 (each (b,c,n) written exactly once)
                    ushort4 h;
                    h.x = f2b(v.x); h.y = f2b(v.y); h.z = f2b(v.z); h.w = f2b(v.w);
                    *(ushort4*)(xbf + ((size_t)(b * C_ + c0 + cc)) * N_ + n0 + nn4) = h;
                }
            }
        }
#pragma unroll
        for (int rep = 0; rep < 4; ++rep) {
            int idx4 = rep * 256 + t;
            int cc = idx4 >> 4;
            int oo4 = (idx4 & 15) << 2;
            *(float4*)(wsh + cc * 64 + oo4) =
                *(const float4*)(wt + (size_t)(c0 + cc) * 128 + oc0 + oo4);
        }
        __syncthreads();
#pragma unroll 8
        for (int cc = 0; cc < 64; ++cc) {
            float4 xa = *(const float4*)(xs + cc * 64 + (tn << 2));
            float4 wa = *(const float4*)(wsh + cc * 64 + (to << 2));
            acc[0][0] += xa.x * wa.x; acc[0][1] += xa.x * wa.y;
            acc[0][2] += xa.x * wa.z; acc[0][3] += xa.x * wa.w;
            acc[1][0] += xa.y * wa.x; acc[1][1] += xa.y * wa.y;
            acc[1][2] += xa.y * wa.z; acc[1][3] += xa.y * wa.w;
            acc[2][0] += xa.z * wa.x; acc[2][1] += xa.z * wa.y;
            acc[2][2] += xa.z * wa.z; acc[2][3] += xa.z * wa.w;
            acc[3][0] += xa.w * wa.x; acc[3][1] += xa.w * wa.y;
            acc[3][2] += xa.w * wa.z; acc[3][3] += xa.w * wa.w;
        }
    }

    float b0 = bcat[oc0 + (to << 2) + 0];
    float b1 = bcat[oc0 + (to << 2) + 1];
    float b2 = bcat[oc0 + (to << 2) + 2];
    float b3 = bcat[oc0 + (to << 2) + 3];
    u16* dst = (og == 0) ? Qb : Kb;
#pragma unroll
    for (int i = 0; i < 4; ++i) {
        int n = n0 + (tn << 2) + i;
        ushort4 h;
        h.x = f2b(acc[i][0] + b0); h.y = f2b(acc[i][1] + b1);
        h.z = f2b(acc[i][2] + b2); h.w = f2b(acc[i][3] + b3);
        *(ushort4*)(dst + ((size_t)b * N_ + n) * 64 + (to << 2)) = h;
    }
}

// ---------------- kernel 3: MFMA single-pass attention + fused vw epilogue --------
// grid (64, 8) remapped XCD-bijectively, 512 threads (8 waves), 2 blocks/CU.
// Block: i-rows [i0, i0+64). Wave w: p_compute tile (rt=w&3 -> 16 i-rows,
// h2=w>>2 -> 64-j half of the 128-j tile); PV/epilogue c-slice [64w, 64w+64).
// LDS layout (byte offsets):
#define KSA_OFF  0        // K buf A [128][72]u16  18432 B
#define KSB_OFF  18432    // K buf B [128][72]u16  18432 B
#define PSA_OFF  36864    // P buf A [64][136]u16  17408 B
#define PSB_OFF  54272    // P buf B [64][136]u16  17408 B
#define YS_OFF   0        // epilogue ys [64][520]u16  66560 B (overlays KS/Ps)
#define LP_OFF   71680    // lpart [64][2] float      512 B
#define SMEM3    72192

#define SHIFT_C 20.0f     // softmax constant shift (overflow guard; result-invariant)

__global__ __launch_bounds__(512, 4) void attn_mfma(
        const u16* __restrict__ Qb, const u16* __restrict__ Kb,
        const u16* __restrict__ xbfw, const void* __restrict__ xin,
        const int* __restrict__ flagp,
        const u16* __restrict__ vwb, const float* __restrict__ vbf,
        const float* __restrict__ gf, void* __restrict__ outv) {
    __shared__ __align__(16) char smem[SMEM3];
    u16* KsA = (u16*)(smem + KSA_OFF);
    u16* KsB = (u16*)(smem + KSB_OFF);
    u16* PsA = (u16*)(smem + PSA_OFF);
    u16* PsB = (u16*)(smem + PSB_OFF);
    u16* ys  = (u16*)(smem + YS_OFF);
    float* lpart = (float*)(smem + LP_OFF);

    const u16*   xb = (const u16*)xin;
    const float* xf = (const float*)xin;
    const int fl = *flagp;
    const u16* xb16 = fl ? (const u16*)xin : xbfw;   // bf16 view of x

    const int t = threadIdx.x;
    const int wv = t >> 6;
    const int lane = t & 63;
    const int L = lane & 15;
    const int q = lane >> 4;
    const int rt = wv & 3;            // i-subtile
    const int h2 = wv >> 2;           // j-half (64-wide) of the 128-j tile

    // XCD-bijective remap: batch b pinned to XCD b (512 blocks, 512%8==0).
    const int gid  = blockIdx.y * 64 + blockIdx.x;
    const int ngid = (gid & 7) * 64 + (gid >> 3);
    const int b  = ngid >> 6;
    const int i0 = (ngid & 63) * 64;

    // Q fragments for this wave's 16 S-rows (i = i0 + 16rt + L)
    const u16* qp = Qb + ((size_t)b * N_ + i0 + 16 * rt + L) * 64;
    bf16x8 qf0 = *(const bf16x8*)(qp + 8 * q);
    bf16x8 qf1 = *(const bf16x8*)(qp + 32 + 8 * q);

    // per-lane partial row sums of exp(S - SHIFT_C); lane row i = 16rt+4q+r
    float lsum[4];
#pragma unroll
    for (int r = 0; r < 4; ++r) lsum[r] = 0.f;

    // acc[mt][nt]: y[c = 64wv+16mt+4q+r][i = 16nt+L]
    f32x4 acc[4][4];
#pragma unroll
    for (int a = 0; a < 4; ++a)
#pragma unroll
        for (int nb = 0; nb < 4; ++nb) acc[a][nb] = (f32x4){0.f, 0.f, 0.f, 0.f};

    const int krow = t >> 2, kcol = (t & 3) * 16;   // K staging: 128 rows x 64 c
    const u16* xrow = xb16 + ((size_t)(b * C_ + 64 * wv + L)) * N_ + 8 * q;

    // p_compute in h-PAIRS: sv[2] live (frees ~8 VGPR vs sv[4]), exp issued early.
    auto p_compute = [&](int jt) {
        const u16* kcur = (jt & 1) ? KsB : KsA;
        u16* psw = (jt & 1) ? PsB : PsA;
#pragma unroll
        for (int hp = 0; hp < 2; ++hp) {
            f32x4 sv[2];
#pragma unroll
            for (int hh = 0; hh < 2; ++hh) {
                int h = hp * 2 + hh;
                const u16* kr = kcur + (64 * h2 + 16 * h + L) * 72;
                bf16x8 k0 = *(const bf16x8*)(kr + 8 * q);
                bf16x8 k1 = *(const bf16x8*)(kr + 32 + 8 * q);
                f32x4 z = {0.f, 0.f, 0.f, 0.f};
                z = __builtin_amdgcn_mfma_f32_16x16x32_bf16(qf0, k0, z, 0, 0, 0);
                z = __builtin_amdgcn_mfma_f32_16x16x32_bf16(qf1, k1, z, 0, 0, 0);
                sv[hh] = z;
            }
#pragma unroll
            for (int hh = 0; hh < 2; ++hh) {
                int h = hp * 2 + hh;
#pragma unroll
                for (int r = 0; r < 4; ++r) {
                    float p = __expf(sv[hh][r] - SHIFT_C);   // unnormalized
                    lsum[r] += p;
                    psw[(16 * rt + 4 * q + r) * 136 + 64 * h2 + 16 * h + L] = f2b(p);
                }
            }
        }
    };

    // pv_step takes the ks=0 af batch preloaded (hoisted before p_compute).
    auto pv_step = [&](int jtp, const bf16x8* af0) {
        const u16* psr = (jtp & 1) ? PsB : PsA;
        const int j0pv = jtp << 7;
#pragma unroll
        for (int ks = 0; ks < 4; ++ks) {
            bf16x8 af[4];
            if (ks == 0) {
#pragma unroll
                for (int mt = 0; mt < 4; ++mt) af[mt] = af0[mt];
            } else {
#pragma unroll
                for (int mt = 0; mt < 4; ++mt)
                    af[mt] = *(const bf16x8*)(xrow + (size_t)(16 * mt) * N_
                                              + j0pv + 32 * ks);
            }
            __builtin_amdgcn_s_setprio(1);
#pragma unroll
            for (int nt = 0; nt < 4; ++nt) {
                bf16x8 pb = *(const bf16x8*)(psr + (16 * nt + L) * 136 + 32 * ks + 8 * q);
#pragma unroll
                for (int mt = 0; mt < 4; ++mt)
                    acc[mt][nt] = __builtin_amdgcn_mfma_f32_16x16x32_bf16(
                        af[mt], pb, acc[mt][nt], 0, 0, 0);
            }
            __builtin_amdgcn_s_setprio(0);
        }
    };

    {   // stage K tile 0 -> KsA (512 thr x 2 uint4: 128 rows x 64 c)
        const u16* kp = Kb + ((size_t)b * N_ + krow) * 64 + kcol;
        *(uint4*)(KsA + krow * 72 + kcol)     = *(const uint4*)kp;
        *(uint4*)(KsA + krow * 72 + kcol + 8) = *(const uint4*)(kp + 8);
    }
    {   // peeled jt = 0: P(0) only (no pv yet)
        const u16* kp = Kb + ((size_t)b * N_ + 128 + krow) * 64 + kcol;
        uint4 kr0 = *(const uint4*)kp;
        uint4 kr1 = *(const uint4*)(kp + 8);
        __syncthreads();
        p_compute(0);
        *(uint4*)(KsB + krow * 72 + kcol)     = kr0;
        *(uint4*)(KsB + krow * 72 + kcol + 8) = kr1;
    }
    for (int jt = 1; jt < 32; ++jt) {
        uint4 kr0 = {0, 0, 0, 0}, kr1 = {0, 0, 0, 0};
        if (jt < 31) {   // prefetch K tile jt+1 (issued pre-barrier)
            const u16* kp = Kb + ((size_t)b * N_ + (jt + 1) * 128 + krow) * 64 + kcol;
            kr0 = *(const uint4*)kp;
            kr1 = *(const uint4*)(kp + 8);
        }
        __syncthreads();
        // hoisted af batch (ks=0) for pv_step(jt-1): latency hides under p_compute
        bf16x8 af0[4];
        {
            const int j0pv = (jt - 1) << 7;
#pragma unroll
            for (int mt = 0; mt < 4; ++mt)
                af0[mt] = *(const bf16x8*)(xrow + (size_t)(16 * mt) * N_ + j0pv);
        }
        p_compute(jt);
        if (jt < 31) {
            u16* kn = ((jt + 1) & 1) ? KsB : KsA;
            *(uint4*)(kn + krow * 72 + kcol)     = kr0;
            *(uint4*)(kn + krow * 72 + kcol + 8) = kr1;
        }
        pv_step(jt - 1, af0);
    }
    __syncthreads();
    {   // flush the pipelined tile
        bf16x8 af0[4];
        const int j0pv = 31 << 7;
#pragma unroll
        for (int mt = 0; mt < 4; ++mt)
            af0[mt] = *(const bf16x8*)(xrow + (size_t)(16 * mt) * N_ + j0pv);
        pv_step(31, af0);
    }

    // ---- finalize l: reduce own-row partials over L lanes, combine j-halves -------
#pragma unroll
    for (int r = 0; r < 4; ++r) {
#pragma unroll
        for (int off = 8; off > 0; off >>= 1)
            lsum[r] += __shfl_xor(lsum[r], off, 64);
    }
    if (L == 0) {
#pragma unroll
        for (int r = 0; r < 4; ++r)
            lpart[(16 * rt + 4 * q + r) * 2 + h2] = lsum[r];
    }
    __syncthreads();   // lpart visible; all Ps/Ks reads done (ys overlay safe)

    float fi[4];
#pragma unroll
    for (int nt = 0; nt < 4; ++nt) {
        int i = 16 * nt + L;
        fi[nt] = 1.0f / (lpart[i * 2] + lpart[i * 2 + 1]);
    }

    // ---- fused epilogue: z = vw @ y, out = gamma*(z+vb) + x ----
    // Write y (scaled by 1/l) once to ys[i][c], then barrier-free kc-GEMM.
#pragma unroll
    for (int mt = 0; mt < 4; ++mt)
#pragma unroll
        for (int nt = 0; nt < 4; ++nt) {
            ushort4 h;
            h.x = f2b(acc[mt][nt][0] * fi[nt]); h.y = f2b(acc[mt][nt][1] * fi[nt]);
            h.z = f2b(acc[mt][nt][2] * fi[nt]); h.w = f2b(acc[mt][nt][3] * fi[nt]);
            *(ushort4*)(ys + (16 * nt + L) * 520 + 64 * wv + 16 * mt + 4 * q) = h;
        }
    __syncthreads();

    const float gma = gf[0];
    f32x4 z[4][4];
#pragma unroll
    for (int a = 0; a < 4; ++a)
#pragma unroll
        for (int nb = 0; nb < 4; ++nb) z[a][nb] = (f32x4){0.f, 0.f, 0.f, 0.f};

#pragma unroll 1
    for (int kc = 0; kc < 8; ++kc) {
#pragma unroll
        for (int nn = 0; nn < 4; ++nn) {
            const u16* yr = ys + (16 * nn + L) * 520 + kc * 64;
            bf16x8 yb0 = *(const bf16x8*)(yr + 8 * q);
            bf16x8 yb1 = *(const bf16x8*)(yr + 32 + 8 * q);
#pragma unroll
            for (int mtp = 0; mtp < 4; ++mtp) {
                int crow = 64 * wv + 16 * mtp + L;
                const u16* wp = vwb + (size_t)crow * C_ + kc * 64;
                bf16x8 a0 = *(const bf16x8*)(wp + 8 * q);
                bf16x8 a1 = *(const bf16x8*)(wp + 32 + 8 * q);
                z[mtp][nn] = __builtin_amdgcn_mfma_f32_16x16x32_bf16(
                    a0, yb0, z[mtp][nn], 0, 0, 0);
                z[mtp][nn] = __builtin_amdgcn_mfma_f32_16x16x32_bf16(
                    a1, yb1, z[mtp][nn], 0, 0, 0);
            }
        }
    }
    // store
#pragma unroll
    for (int mtp = 0; mtp < 4; ++mtp)
#pragma unroll
        for (int nn = 0; nn < 4; ++nn)
#pragma unroll
            for (int r = 0; r < 4; ++r) {
                int cp = 64 * wv + 16 * mtp + 4 * q + r;
                int ii = i0 + 16 * nn + L;
                size_t oi = ((size_t)(b * C_ + cp)) * N_ + ii;
                float val = gma * (z[mtp][nn][r] + vbf[cp]);
                if (fl) ((u16*)outv)[oi] = f2b(val + b2f(xb[oi]));
                else    ((float*)outv)[oi] = val + xf[oi];
            }
}

extern "C" void kernel_launch(void* const* d_in, const int* in_sizes, int n_in,
                              void* d_out, int out_size, void* d_ws, size_t ws_size,
                              hipStream_t stream) {
    const void* x  = d_in[0];
    const void* qw = d_in[1];
    const void* qb = d_in[2];
    const void* kw = d_in[3];
    const void* kb = d_in[4];
    const void* vw = d_in[5];
    const void* vb = d_in[6];
    const void* gm = d_in[7];

    char* ws = (char*)d_ws;
    int*   flag = (int*)(ws + 0);
    float* gf   = (float*)(ws + 16);
    float* bcat = (float*)(ws + 32);
    float* vbf  = (float*)(ws + 544);
    float* wt   = (float*)(ws + 2592);
    u16*   Qb   = (u16*)(ws + 264736);
    u16*   Kb   = (u16*)(ws + 4459040);
    u16*   vwb  = (u16*)(ws + 8653344);
    u16*   xbf  = (u16*)(ws + 9177632);   // total ws use: 42,732,064 B

    detect_dtype<<<dim3(1), dim3(256), 0, stream>>>((const u16*)x, flag);
    prep_params<<<dim3(256), dim3(256), 0, stream>>>(
        qw, qb, kw, kb, vb, gm, vw, flag, wt, bcat, vbf, gf, vwb);
    proj_qk<<<dim3(2, 64, 8), dim3(256), 0, stream>>>(x, flag, wt, bcat, Qb, Kb, xbf);
    attn_mfma<<<dim3(64, 8), dim3(512), 0, stream>>>(
        Qb, Kb, xbf, x, flag, vwb, vbf, gf, d_out);
}

// Round 10
// 519.673 us; speedup vs baseline: 1.1374x; 1.1374x over previous
//
#include <hip/hip_runtime.h>
#include <stdint.h>

// PAM_Module: B=8, C=512, H=W=64 -> N=4096, O=64. Dtype auto-detected (bf16 vs fp32).
// out = gamma * (vw @ (xf @ att^T) + vb) + x   (softmax rows sum to 1 => vb passes through)
// MFMA pipeline:
//   K0 detect, K1 prep (wt/bcat/vbf/gf fp32 + vw->bf16 vwb),
//   K2 proj -> Qb,Kb bf16 [b][n][64] (fp32 path also writes xbf; bf16 aliases x),
//   K3 attn_mfma: single-pass shifted-exp softmax + PV + fused vw-GEMM epilogue.
//
// R10 (fund the af hoist properly; R9's array-hoist spilled: WRITE 79e3->213e3):
//  - K staging via __builtin_amdgcn_global_load_lds (16B): zero prefetch regs
//    (-8 VGPR), no ds_write in wave stream, async with a FULL iteration of cover.
//    K LDS becomes linear [128][64] with XOR swizzle BOTH sides (rule #21):
//    inverse-swizzled per-lane GLOBAL source (col = ((l&7)^(l>>3))<<4) + swizzled
//    read offset ((16q)^((L&7)<<4)) -> conflict-free ds_read_b128.
//  - h-pair p_compute (sv[2] live, -8 VGPR).
//  - ks=0 af batch hoisted as 4 NAMED bf16x8 (no array/pointer, rule #20),
//    issued post-barrier, consumed after p_compute. 16 spent = 16 freed.
// Keeps R8 shape: 64-i blocks, 512 thr, j-tile 128, acc[4][4] (64 AGPR),
// __launch_bounds__(512,4) -> 2 blocks/CU, XCD-pinned batches, depth-2 pipeline.
// ws: flag@0 gf@16 bcat@32 vbf@544 wt@2592 Qb@264736 Kb@4459040 vwb@8653344
//     xbf@9177632  (total 42,732,064 B)

#define B_ 8
#define C_ 512
#define N_ 4096

typedef unsigned short u16;
typedef unsigned int u32;
typedef __attribute__((ext_vector_type(8))) short bf16x8;
typedef __attribute__((ext_vector_type(4))) float f32x4;

static __device__ __forceinline__ float b2f(u16 u) {
    return __uint_as_float(((u32)u) << 16);
}
static __device__ __forceinline__ u16 f2b(float f) {
    u32 u = __float_as_uint(f);
    u = u + 0x7fffu + ((u >> 16) & 1u);   // RNE
    return (u16)(u >> 16);
}
static __device__ __forceinline__ float ldf(const void* p, size_t i, int fl) {
    return fl ? b2f(((const u16*)p)[i]) : ((const float*)p)[i];
}
static __device__ __forceinline__ void glds16(const void* g, void* l) {
    __builtin_amdgcn_global_load_lds(
        (const __attribute__((address_space(1))) unsigned int*)g,
        (__attribute__((address_space(3))) unsigned int*)l, 16, 0, 0);
}

// ---------------- kernel 0: dtype detector ----------------------------------------
__global__ void detect_dtype(const u16* __restrict__ x, int* __restrict__ flag) {
    __shared__ int cnt[256];
    int t = threadIdx.x;
    int c = 0;
    for (int i = t; i < 4096; i += 256) {
        int e = (x[i] >> 7) & 0xFF;
        if (e >= 95 && e <= 140) c++;
    }
    cnt[t] = c;
    __syncthreads();
    for (int s = 128; s > 0; s >>= 1) {
        if (t < s) cnt[t] += cnt[t + s];
        __syncthreads();
    }
    if (t == 0) *flag = (cnt[0] >= 3686) ? 1 : 0;   // 1 = bf16, 0 = fp32
}

// ---------------- kernel 1: params -> fp32 ws, vw -> bf16 --------------------------
__global__ void prep_params(const void* __restrict__ qw, const void* __restrict__ qb,
                            const void* __restrict__ kw, const void* __restrict__ kb,
                            const void* __restrict__ vb, const void* __restrict__ gm,
                            const void* __restrict__ vw, const int* __restrict__ flagp,
                            float* __restrict__ wt, float* __restrict__ bcat,
                            float* __restrict__ vbf, float* __restrict__ gf,
                            u16* __restrict__ vwb) {
    int fl = *flagp;
    int gid = blockIdx.x * 256 + threadIdx.x;   // grid 256*256 = 65536
    if (gid < C_ * 128) {
        int c = gid >> 7, o = gid & 127;
        wt[c * 128 + o] = (o < 64) ? ldf(qw, (size_t)o * C_ + c, fl)
                                   : ldf(kw, (size_t)(o - 64) * C_ + c, fl);
    }
    if (gid < 128) bcat[gid] = (gid < 64) ? ldf(qb, gid, fl) : ldf(kb, gid - 64, fl);
    if (gid < C_) vbf[gid] = ldf(vb, gid, fl);
    if (gid == 0) gf[0] = ldf(gm, 0, fl);
    {   // vw -> bf16: 65536 threads x 4 elems = 262144 = C*C
        int v0 = gid * 4;
        ushort4 h;
        h.x = f2b(ldf(vw, v0 + 0, fl));
        h.y = f2b(ldf(vw, v0 + 1, fl));
        h.z = f2b(ldf(vw, v0 + 2, fl));
        h.w = f2b(ldf(vw, v0 + 3, fl));
        *(ushort4*)(vwb + v0) = h;
    }
}

// ---------------- kernel 2: Q/K projection -> bf16, grid (2, 64, 8) ---------------
// fp32 input: og==0 blocks also emit x as bf16 into xbf (fused xconv).
__global__ __launch_bounds__(256) void proj_qk(
        const void* __restrict__ xin, const int* __restrict__ flagp,
        const float* __restrict__ wt, const float* __restrict__ bcat,
        u16* __restrict__ Qb, u16* __restrict__ Kb, u16* __restrict__ xbf) {
    __shared__ __align__(16) char smem[32768];
    float* xs  = (float*)smem;            // [64][64]
    float* wsh = (float*)(smem + 16384);  // [64][64]
    const u16*   xb = (const u16*)xin;
    const float* xf = (const float*)xin;
    int fl = *flagp;

    int t = threadIdx.x;
    int og = blockIdx.x;
    int n0 = blockIdx.y * 64;
    int b  = blockIdx.z;
    int oc0 = og * 64;
    int tn = t & 15, to = t >> 4;

    float acc[4][4];
#pragma unroll
    for (int i = 0; i < 4; ++i)
#pragma unroll
        for (int j = 0; j < 4; ++j) acc[i][j] = 0.f;

    for (int c0 = 0; c0 < C_; c0 += 64) {
        __syncthreads();
        if (fl) {
#pragma unroll
            for (int rep = 0; rep < 4; ++rep) {
                int idx4 = rep * 256 + t;
                int cc = idx4 >> 4;
                int nn4 = (idx4 & 15) << 2;
                ushort4 uv = *(const ushort4*)(xb + ((size_t)(b * C_ + c0 + cc)) * N_ + n0 + nn4);
                float4 f;
                f.x = b2f(uv.x); f.y = b2f(uv.y); f.z = b2f(uv.z); f.w = b2f(uv.w);
                *(float4*)(xs + cc * 64 + nn4) = f;
            }
        } else {
#pragma unroll
            for (int rep = 0; rep < 4; ++rep) {
                int idx4 = rep * 256 + t;
                int cc = idx4 >> 4;
                int nn4 = (idx4 & 15) << 2;
                float4 v = *(const float4*)(xf + ((size_t)(b * C_ + c0 + cc)) * N_ + n0 + nn4);
                *(float4*)(xs + cc * 64 + nn4) = v;
                if (og == 0) {   // fused x -> bf16 (each (b,c,n) written exactly once)
                    ushort4 h;
                    h.x = f2b(v.x); h.y = f2b(v.y); h.z = f2b(v.z); h.w = f2b(v.w);
                    *(ushort4*)(xbf + ((size_t)(b * C_ + c0 + cc)) * N_ + n0 + nn4) = h;
                }
            }
        }
#pragma unroll
        for (int rep = 0; rep < 4; ++rep) {
            int idx4 = rep * 256 + t;
            int cc = idx4 >> 4;
            int oo4 = (idx4 & 15) << 2;
            *(float4*)(wsh + cc * 64 + oo4) =
                *(const float4*)(wt + (size_t)(c0 + cc) * 128 + oc0 + oo4);
        }
        __syncthreads();
#pragma unroll 8
        for (int cc = 0; cc < 64; ++cc) {
            float4 xa = *(const float4*)(xs + cc * 64 + (tn << 2));
            float4 wa = *(const float4*)(wsh + cc * 64 + (to << 2));
            acc[0][0] += xa.x * wa.x; acc[0][1] += xa.x * wa.y;
            acc[0][2] += xa.x * wa.z; acc[0][3] += xa.x * wa.w;
            acc[1][0] += xa.y * wa.x; acc[1][1] += xa.y * wa.y;
            acc[1][2] += xa.y * wa.z; acc[1][3] += xa.y * wa.w;
            acc[2][0] += xa.z * wa.x; acc[2][1] += xa.z * wa.y;
            acc[2][2] += xa.z * wa.z; acc[2][3] += xa.z * wa.w;
            acc[3][0] += xa.w * wa.x; acc[3][1] += xa.w * wa.y;
            acc[3][2] += xa.w * wa.z; acc[3][3] += xa.w * wa.w;
        }
    }

    float b0 = bcat[oc0 + (to << 2) + 0];
    float b1 = bcat[oc0 + (to << 2) + 1];
    float b2 = bcat[oc0 + (to << 2) + 2];
    float b3 = bcat[oc0 + (to << 2) + 3];
    u16* dst = (og == 0) ? Qb : Kb;
#pragma unroll
    for (int i = 0; i < 4; ++i) {
        int n = n0 + (tn << 2) + i;
        ushort4 h;
        h.x = f2b(acc[i][0] + b0); h.y = f2b(acc[i][1] + b1);
        h.z = f2b(acc[i][2] + b2); h.w = f2b(acc[i][3] + b3);
        *(ushort4*)(dst + ((size_t)b * N_ + n) * 64 + (to << 2)) = h;
    }
}

// ---------------- kernel 3: MFMA single-pass attention + fused vw epilogue --------
// grid (64, 8) remapped XCD-bijectively, 512 threads (8 waves), 2 blocks/CU.
// Block: i-rows [i0, i0+64). Wave w: p_compute tile (rt=w&3 -> 16 i-rows,
// h2=w>>2 -> 64-j half of the 128-j tile); PV/epilogue c-slice [64w, 64w+64).
// K LDS is linear [128][64]u16 with 16B-granule XOR swizzle:
//   LDS[row*128 + (c ^ ((row&7)<<4))] = K[row][c]  (c = byte col, mult of 16)
// staged by global_load_lds with inverse-swizzled per-lane global source.
// LDS layout (byte offsets):
#define KSA_OFF  0        // K buf A [128][64]u16  16384 B (swizzled)
#define KSB_OFF  16384    // K buf B [128][64]u16  16384 B
#define PSA_OFF  32768    // P buf A [64][136]u16  17408 B
#define PSB_OFF  50176    // P buf B [64][136]u16  17408 B
#define YS_OFF   0        // epilogue ys [64][520]u16  66560 B (overlays KS/Ps)
#define LP_OFF   67584    // lpart [64][2] float      512 B
#define SMEM3    68096

#define SHIFT_C 20.0f     // softmax constant shift (overflow guard; result-invariant)

__global__ __launch_bounds__(512, 4) void attn_mfma(
        const u16* __restrict__ Qb, const u16* __restrict__ Kb,
        const u16* __restrict__ xbfw, const void* __restrict__ xin,
        const int* __restrict__ flagp,
        const u16* __restrict__ vwb, const float* __restrict__ vbf,
        const float* __restrict__ gf, void* __restrict__ outv) {
    __shared__ __align__(16) char smem[SMEM3];
    char* KsA = smem + KSA_OFF;
    char* KsB = smem + KSB_OFF;
    u16* PsA = (u16*)(smem + PSA_OFF);
    u16* PsB = (u16*)(smem + PSB_OFF);
    u16* ys  = (u16*)(smem + YS_OFF);
    float* lpart = (float*)(smem + LP_OFF);

    const u16*   xb = (const u16*)xin;
    const float* xf = (const float*)xin;
    const int fl = *flagp;
    const u16* xb16 = fl ? (const u16*)xin : xbfw;   // bf16 view of x

    const int t = threadIdx.x;
    const int wv = t >> 6;
    const int lane = t & 63;
    const int L = lane & 15;
    const int q = lane >> 4;
    const int rt = wv & 3;            // i-subtile
    const int h2 = wv >> 2;           // j-half (64-wide) of the 128-j tile

    // XCD-bijective remap: batch b pinned to XCD b (512 blocks, 512%8==0).
    const int gid  = blockIdx.y * 64 + blockIdx.x;
    const int ngid = (gid & 7) * 64 + (gid >> 3);
    const int b  = ngid >> 6;
    const int i0 = (ngid & 63) * 64;

    // Q fragments for this wave's 16 S-rows (i = i0 + 16rt + L)
    const u16* qp = Qb + ((size_t)b * N_ + i0 + 16 * rt + L) * 64;
    bf16x8 qf0 = *(const bf16x8*)(qp + 8 * q);
    bf16x8 qf1 = *(const bf16x8*)(qp + 32 + 8 * q);

    // per-lane partial row sums of exp(S - SHIFT_C); lane row i = 16rt+4q+r
    float lsum[4];
#pragma unroll
    for (int r = 0; r < 4; ++r) lsum[r] = 0.f;

    // acc[mt][nt]: y[c = 64wv+16mt+4q+r][i = 16nt+L]
    f32x4 acc[4][4];
#pragma unroll
    for (int a = 0; a < 4; ++a)
#pragma unroll
        for (int nb = 0; nb < 4; ++nb) acc[a][nb] = (f32x4){0.f, 0.f, 0.f, 0.f};

    // K staging (global_load_lds): wave w stages rows 16w..16w+15 (2 x 1KB).
    // lane l covers LDS linear off 16*l; src col inverse-swizzled.
    const int lane8 = lane >> 3;                       // 0..7
    const int kofs = (16 * wv + lane8) * 128 + ((((lane & 7) ^ lane8)) << 4);
    const char* ksrc0 = (const char*)Kb + ((size_t)b * N_) * 128 + kofs;
    char* kdstA = KsA + wv * 2048;
    char* kdstB = KsB + wv * 2048;
    // K read offsets (swizzled): row = 64h2+16h+L -> row&7 = L&7
    const int swzL = (L & 7) << 4;
    const int krd0 = L * 128 + ((16 * q) ^ swzL);
    const int krd1 = L * 128 + ((64 + 16 * q) ^ swzL);

    const u16* xrow = xb16 + ((size_t)(b * C_ + 64 * wv + L)) * N_ + 8 * q;

    auto stageK = [&](int jt) {   // stage K tile jt -> Ks[jt&1] (async)
        char* kd = (jt & 1) ? kdstB : kdstA;
        const char* gs = ksrc0 + (size_t)jt * 16384;
        glds16(gs, kd);
        glds16(gs + 1024, kd + 1024);
    };

    // p_compute in h-PAIRS: sv[2] live, exp issued early.
    auto p_compute = [&](int jt) {
        const char* kcur = (jt & 1) ? KsB : KsA;
        u16* psw = (jt & 1) ? PsB : PsA;
#pragma unroll
        for (int hp = 0; hp < 2; ++hp) {
            f32x4 sv[2];
#pragma unroll
            for (int hh = 0; hh < 2; ++hh) {
                int h = hp * 2 + hh;
                const char* kr = kcur + (64 * h2 + 16 * h) * 128;
                bf16x8 k0 = *(const bf16x8*)(kr + krd0);
                bf16x8 k1 = *(const bf16x8*)(kr + krd1);
                f32x4 z = {0.f, 0.f, 0.f, 0.f};
                z = __builtin_amdgcn_mfma_f32_16x16x32_bf16(qf0, k0, z, 0, 0, 0);
                z = __builtin_amdgcn_mfma_f32_16x16x32_bf16(qf1, k1, z, 0, 0, 0);
                sv[hh] = z;
            }
#pragma unroll
            for (int hh = 0; hh < 2; ++hh) {
                int h = hp * 2 + hh;
#pragma unroll
                for (int r = 0; r < 4; ++r) {
                    float p = __expf(sv[hh][r] - SHIFT_C);   // unnormalized
                    lsum[r] += p;
                    psw[(16 * rt + 4 * q + r) * 136 + 64 * h2 + 16 * h + L] = f2b(p);
                }
            }
        }
    };

    // pv_step with ks=0 af batch passed as 4 NAMED values (hoisted pre-p_compute).
    auto pv_step = [&](int jtp, bf16x8 ha0, bf16x8 ha1, bf16x8 ha2, bf16x8 ha3) {
        const u16* psr = (jtp & 1) ? PsB : PsA;
        const int j0pv = jtp << 7;
#pragma unroll
        for (int ks = 0; ks < 4; ++ks) {
            bf16x8 af0v, af1v, af2v, af3v;
            if (ks == 0) {
                af0v = ha0; af1v = ha1; af2v = ha2; af3v = ha3;
            } else {
                af0v = *(const bf16x8*)(xrow + (size_t)(0)  * N_ + j0pv + 32 * ks);
                af1v = *(const bf16x8*)(xrow + (size_t)(16) * N_ + j0pv + 32 * ks);
                af2v = *(const bf16x8*)(xrow + (size_t)(32) * N_ + j0pv + 32 * ks);
                af3v = *(const bf16x8*)(xrow + (size_t)(48) * N_ + j0pv + 32 * ks);
            }
            __builtin_amdgcn_s_setprio(1);
#pragma unroll
            for (int nt = 0; nt < 4; ++nt) {
                bf16x8 pb = *(const bf16x8*)(psr + (16 * nt + L) * 136 + 32 * ks + 8 * q);
                acc[0][nt] = __builtin_amdgcn_mfma_f32_16x16x32_bf16(
                    af0v, pb, acc[0][nt], 0, 0, 0);
                acc[1][nt] = __builtin_amdgcn_mfma_f32_16x16x32_bf16(
                    af1v, pb, acc[1][nt], 0, 0, 0);
                acc[2][nt] = __builtin_amdgcn_mfma_f32_16x16x32_bf16(
                    af2v, pb, acc[2][nt], 0, 0, 0);
                acc[3][nt] = __builtin_amdgcn_mfma_f32_16x16x32_bf16(
                    af3v, pb, acc[3][nt], 0, 0, 0);
            }
            __builtin_amdgcn_s_setprio(0);
        }
    };

    // prologue: stage K0, K1 async; barrier drains both.
    stageK(0);
    stageK(1);
    __syncthreads();
    p_compute(0);

    for (int jt = 1; jt < 32; ++jt) {
        __syncthreads();   // all waves done p_compute(jt-1) & pv_step(jt-2)
        if (jt < 31) stageK(jt + 1);   // async into Ks[(jt+1)&1] (dead buffer)
        // hoisted ks=0 af batch for pv_step(jt-1): latency hides under p_compute
        const int j0h = (jt - 1) << 7;
        bf16x8 ha0 = *(const bf16x8*)(xrow + (size_t)(0)  * N_ + j0h);
        bf16x8 ha1 = *(const bf16x8*)(xrow + (size_t)(16) * N_ + j0h);
        bf16x8 ha2 = *(const bf16x8*)(xrow + (size_t)(32) * N_ + j0h);
        bf16x8 ha3 = *(const bf16x8*)(xrow + (size_t)(48) * N_ + j0h);
        p_compute(jt);
        pv_step(jt - 1, ha0, ha1, ha2, ha3);
    }
    {   // flush the pipelined tile
        const int j0h = 31 << 7;
        bf16x8 ha0 = *(const bf16x8*)(xrow + (size_t)(0)  * N_ + j0h);
        bf16x8 ha1 = *(const bf16x8*)(xrow + (size_t)(16) * N_ + j0h);
        bf16x8 ha2 = *(const bf16x8*)(xrow + (size_t)(32) * N_ + j0h);
        bf16x8 ha3 = *(const bf16x8*)(xrow + (size_t)(48) * N_ + j0h);
        __syncthreads();   // P(31) visibility across waves
        pv_step(31, ha0, ha1, ha2, ha3);
    }

    // ---- finalize l: reduce own-row partials over L lanes, combine j-halves -------
#pragma unroll
    for (int r = 0; r < 4; ++r) {
#pragma unroll
        for (int off = 8; off > 0; off >>= 1)
            lsum[r] += __shfl_xor(lsum[r], off, 64);
    }
    if (L == 0) {
#pragma unroll
        for (int r = 0; r < 4; ++r)
            lpart[(16 * rt + 4 * q + r) * 2 + h2] = lsum[r];
    }
    __syncthreads();   // lpart visible; all Ps/Ks reads done (ys overlay safe)

    float fi[4];
#pragma unroll
    for (int nt = 0; nt < 4; ++nt) {
        int i = 16 * nt + L;
        fi[nt] = 1.0f / (lpart[i * 2] + lpart[i * 2 + 1]);
    }

    // ---- fused epilogue: z = vw @ y, out = gamma*(z+vb) + x ----
    // Write y (scaled by 1/l) once to ys[i][c], then barrier-free kc-GEMM.
#pragma unroll
    for (int mt = 0; mt < 4; ++mt)
#pragma unroll
        for (int nt = 0; nt < 4; ++nt) {
            ushort4 h;
            h.x = f2b(acc[mt][nt][0] * fi[nt]); h.y = f2b(acc[mt][nt][1] * fi[nt]);
            h.z = f2b(acc[mt][nt][2] * fi[nt]); h.w = f2b(acc[mt][nt][3] * fi[nt]);
            *(ushort4*)(ys + (16 * nt + L) * 520 + 64 * wv + 16 * mt + 4 * q) = h;
        }
    __syncthreads();

    const float gma = gf[0];
    f32x4 z[4][4];
#pragma unroll
    for (int a = 0; a < 4; ++a)
#pragma unroll
        for (int nb = 0; nb < 4; ++nb) z[a][nb] = (f32x4){0.f, 0.f, 0.f, 0.f};

#pragma unroll 1
    for (int kc = 0; kc < 8; ++kc) {
#pragma unroll
        for (int nn = 0; nn < 4; ++nn) {
            const u16* yr = ys + (16 * nn + L) * 520 + kc * 64;
            bf16x8 yb0 = *(const bf16x8*)(yr + 8 * q);
            bf16x8 yb1 = *(const bf16x8*)(yr + 32 + 8 * q);
#pragma unroll
            for (int mtp = 0; mtp < 4; ++mtp) {
                int crow = 64 * wv + 16 * mtp + L;
                const u16* wp = vwb + (size_t)crow * C_ + kc * 64;
                bf16x8 a0 = *(const bf16x8*)(wp + 8 * q);
                bf16x8 a1 = *(const bf16x8*)(wp + 32 + 8 * q);
                z[mtp][nn] = __builtin_amdgcn_mfma_f32_16x16x32_bf16(
                    a0, yb0, z[mtp][nn], 0, 0, 0);
                z[mtp][nn] = __builtin_amdgcn_mfma_f32_16x16x32_bf16(
                    a1, yb1, z[mtp][nn], 0, 0, 0);
            }
        }
    }
    // store
#pragma unroll
    for (int mtp = 0; mtp < 4; ++mtp)
#pragma unroll
        for (int nn = 0; nn < 4; ++nn)
#pragma unroll
            for (int r = 0; r < 4; ++r) {
                int cp = 64 * wv + 16 * mtp + 4 * q + r;
                int ii = i0 + 16 * nn + L;
                size_t oi = ((size_t)(b * C_ + cp)) * N_ + ii;
                float val = gma * (z[mtp][nn][r] + vbf[cp]);
                if (fl) ((u16*)outv)[oi] = f2b(val + b2f(xb[oi]));
                else    ((float*)outv)[oi] = val + xf[oi];
            }
}

extern "C" void kernel_launch(void* const* d_in, const int* in_sizes, int n_in,
                              void* d_out, int out_size, void* d_ws, size_t ws_size,
                              hipStream_t stream) {
    const void* x  = d_in[0];
    const void* qw = d_in[1];
    const void* qb = d_in[2];
    const void* kw = d_in[3];
    const void* kb = d_in[4];
    const void* vw = d_in[5];
    const void* vb = d_in[6];
    const void* gm = d_in[7];

    char* ws = (char*)d_ws;
    int*   flag = (int*)(ws + 0);
    float* gf   = (float*)(ws + 16);
    float* bcat = (float*)(ws + 32);
    float* vbf  = (float*)(ws + 544);
    float* wt   = (float*)(ws + 2592);
    u16*   Qb   = (u16*)(ws + 264736);
    u16*   Kb   = (u16*)(ws + 4459040);
    u16*   vwb  = (u16*)(ws + 8653344);
    u16*   xbf  = (u16*)(ws + 9177632);   // total ws use: 42,732,064 B

    detect_dtype<<<dim3(1), dim3(256), 0, stream>>>((const u16*)x, flag);
    prep_params<<<dim3(256), dim3(256), 0, stream>>>(
        qw, qb, kw, kb, vb, gm, vw, flag, wt, bcat, vbf, gf, vwb);
    proj_qk<<<dim3(2, 64, 8), dim3(256), 0, stream>>>(x, flag, wt, bcat, Qb, Kb, xbf);
    attn_mfma<<<dim3(64, 8), dim3(512), 0, stream>>>(
        Qb, Kb, xbf, x, flag, vwb, vbf, gf, d_out);
}

// Round 11
// 492.935 us; speedup vs baseline: 1.1991x; 1.0542x over previous
//
#include <hip/hip_runtime.h>
#include <stdint.h>

// PAM_Module: B=8, C=512, H=W=64 -> N=4096, O=64. Dtype auto-detected (bf16 vs fp32).
// out = gamma * (vw @ (xf @ att^T) + vb) + x   (softmax rows sum to 1 => vb passes through)
// MFMA pipeline:
//   K0 detect, K1 prep (wt/bcat/vbf/gf fp32 + vw->bf16 vwb),
//   K2 proj -> Qb,Kb bf16 [b][n][64] (fp32 path also writes xbf; bf16 aliases x),
//   K3 attn_mfma: single-pass shifted-exp softmax + PV + fused vw-GEMM epilogue.
//
// R11 (vmcnt-order fix of R10): R10 issued stageK glds BEFORE the hoisted af
// loads; vmcnt retires in issue order, so waiting for ha3 before PV ks=0 was
// vmcnt(0) -- draining the just-issued K DMA every iteration (389us, worse than
// R8's 357). Fix: issue ha loads FIRST, then stageK -> wait for ha3 is vmcnt(2),
// K DMA stays in flight with a full iteration of cover.
//  - K staging via global_load_lds (16B, zero prefetch regs), XOR swizzle both
//    sides (rule #21): src col ((l&7)^(l>>3))<<4, read off (16q)^((L&7)<<4).
//  - h-pair p_compute (sv[2] live); ks=0 af batch hoisted as 4 NAMED bf16x8.
// Keeps R8 shape: 64-i blocks, 512 thr, j-tile 128, acc[4][4] (64 AGPR),
// __launch_bounds__(512,4) -> 2 blocks/CU, XCD-pinned batches, depth-2 pipeline.
// ws: flag@0 gf@16 bcat@32 vbf@544 wt@2592 Qb@264736 Kb@4459040 vwb@8653344
//     xbf@9177632  (total 42,732,064 B)

#define B_ 8
#define C_ 512
#define N_ 4096

typedef unsigned short u16;
typedef unsigned int u32;
typedef __attribute__((ext_vector_type(8))) short bf16x8;
typedef __attribute__((ext_vector_type(4))) float f32x4;

static __device__ __forceinline__ float b2f(u16 u) {
    return __uint_as_float(((u32)u) << 16);
}
static __device__ __forceinline__ u16 f2b(float f) {
    u32 u = __float_as_uint(f);
    u = u + 0x7fffu + ((u >> 16) & 1u);   // RNE
    return (u16)(u >> 16);
}
static __device__ __forceinline__ float ldf(const void* p, size_t i, int fl) {
    return fl ? b2f(((const u16*)p)[i]) : ((const float*)p)[i];
}
static __device__ __forceinline__ void glds16(const void* g, void* l) {
    __builtin_amdgcn_global_load_lds(
        (const __attribute__((address_space(1))) unsigned int*)g,
        (__attribute__((address_space(3))) unsigned int*)l, 16, 0, 0);
}

// ---------------- kernel 0: dtype detector ----------------------------------------
__global__ void detect_dtype(const u16* __restrict__ x, int* __restrict__ flag) {
    __shared__ int cnt[256];
    int t = threadIdx.x;
    int c = 0;
    for (int i = t; i < 4096; i += 256) {
        int e = (x[i] >> 7) & 0xFF;
        if (e >= 95 && e <= 140) c++;
    }
    cnt[t] = c;
    __syncthreads();
    for (int s = 128; s > 0; s >>= 1) {
        if (t < s) cnt[t] += cnt[t + s];
        __syncthreads();
    }
    if (t == 0) *flag = (cnt[0] >= 3686) ? 1 : 0;   // 1 = bf16, 0 = fp32
}

// ---------------- kernel 1: params -> fp32 ws, vw -> bf16 --------------------------
__global__ void prep_params(const void* __restrict__ qw, const void* __restrict__ qb,
                            const void* __restrict__ kw, const void* __restrict__ kb,
                            const void* __restrict__ vb, const void* __restrict__ gm,
                            const void* __restrict__ vw, const int* __restrict__ flagp,
                            float* __restrict__ wt, float* __restrict__ bcat,
                            float* __restrict__ vbf, float* __restrict__ gf,
                            u16* __restrict__ vwb) {
    int fl = *flagp;
    int gid = blockIdx.x * 256 + threadIdx.x;   // grid 256*256 = 65536
    if (gid < C_ * 128) {
        int c = gid >> 7, o = gid & 127;
        wt[c * 128 + o] = (o < 64) ? ldf(qw, (size_t)o * C_ + c, fl)
                                   : ldf(kw, (size_t)(o - 64) * C_ + c, fl);
    }
    if (gid < 128) bcat[gid] = (gid < 64) ? ldf(qb, gid, fl) : ldf(kb, gid - 64, fl);
    if (gid < C_) vbf[gid] = ldf(vb, gid, fl);
    if (gid == 0) gf[0] = ldf(gm, 0, fl);
    {   // vw -> bf16: 65536 threads x 4 elems = 262144 = C*C
        int v0 = gid * 4;
        ushort4 h;
        h.x = f2b(ldf(vw, v0 + 0, fl));
        h.y = f2b(ldf(vw, v0 + 1, fl));
        h.z = f2b(ldf(vw, v0 + 2, fl));
        h.w = f2b(ldf(vw, v0 + 3, fl));
        *(ushort4*)(vwb + v0) = h;
    }
}

// ---------------- kernel 2: Q/K projection -> bf16, grid (2, 64, 8) ---------------
// fp32 input: og==0 blocks also emit x as bf16 into xbf (fused xconv).
__global__ __launch_bounds__(256) void proj_qk(
        const void* __restrict__ xin, const int* __restrict__ flagp,
        const float* __restrict__ wt, const float* __restrict__ bcat,
        u16* __restrict__ Qb, u16* __restrict__ Kb, u16* __restrict__ xbf) {
    __shared__ __align__(16) char smem[32768];
    float* xs  = (float*)smem;            // [64][64]
    float* wsh = (float*)(smem + 16384);  // [64][64]
    const u16*   xb = (const u16*)xin;
    const float* xf = (const float*)xin;
    int fl = *flagp;

    int t = threadIdx.x;
    int og = blockIdx.x;
    int n0 = blockIdx.y * 64;
    int b  = blockIdx.z;
    int oc0 = og * 64;
    int tn = t & 15, to = t >> 4;

    float acc[4][4];
#pragma unroll
    for (int i = 0; i < 4; ++i)
#pragma unroll
        for (int j = 0; j < 4; ++j) acc[i][j] = 0.f;

    for (int c0 = 0; c0 < C_; c0 += 64) {
        __syncthreads();
        if (fl) {
#pragma unroll
            for (int rep = 0; rep < 4; ++rep) {
                int idx4 = rep * 256 + t;
                int cc = idx4 >> 4;
                int nn4 = (idx4 & 15) << 2;
                ushort4 uv = *(const ushort4*)(xb + ((size_t)(b * C_ + c0 + cc)) * N_ + n0 + nn4);
                float4 f;
                f.x = b2f(uv.x); f.y = b2f(uv.y); f.z = b2f(uv.z); f.w = b2f(uv.w);
                *(float4*)(xs + cc * 64 + nn4) = f;
            }
        } else {
#pragma unroll
            for (int rep = 0; rep < 4; ++rep) {
                int idx4 = rep * 256 + t;
                int cc = idx4 >> 4;
                int nn4 = (idx4 & 15) << 2;
                float4 v = *(const float4*)(xf + ((size_t)(b * C_ + c0 + cc)) * N_ + n0 + nn4);
                *(float4*)(xs + cc * 64 + nn4) = v;
                if (og == 0) {   // fused x -> bf16 (each (b,c,n) written exactly once)
                    ushort4 h;
                    h.x = f2b(v.x); h.y = f2b(v.y); h.z = f2b(v.z); h.w = f2b(v.w);
                    *(ushort4*)(xbf + ((size_t)(b * C_ + c0 + cc)) * N_ + n0 + nn4) = h;
                }
            }
        }
#pragma unroll
        for (int rep = 0; rep < 4; ++rep) {
            int idx4 = rep * 256 + t;
            int cc = idx4 >> 4;
            int oo4 = (idx4 & 15) << 2;
            *(float4*)(wsh + cc * 64 + oo4) =
                *(const float4*)(wt + (size_t)(c0 + cc) * 128 + oc0 + oo4);
        }
        __syncthreads();
#pragma unroll 8
        for (int cc = 0; cc < 64; ++cc) {
            float4 xa = *(const float4*)(xs + cc * 64 + (tn << 2));
            float4 wa = *(const float4*)(wsh + cc * 64 + (to << 2));
            acc[0][0] += xa.x * wa.x; acc[0][1] += xa.x * wa.y;
            acc[0][2] += xa.x * wa.z; acc[0][3] += xa.x * wa.w;
            acc[1][0] += xa.y * wa.x; acc[1][1] += xa.y * wa.y;
            acc[1][2] += xa.y * wa.z; acc[1][3] += xa.y * wa.w;
            acc[2][0] += xa.z * wa.x; acc[2][1] += xa.z * wa.y;
            acc[2][2] += xa.z * wa.z; acc[2][3] += xa.z * wa.w;
            acc[3][0] += xa.w * wa.x; acc[3][1] += xa.w * wa.y;
            acc[3][2] += xa.w * wa.z; acc[3][3] += xa.w * wa.w;
        }
    }

    float b0 = bcat[oc0 + (to << 2) + 0];
    float b1 = bcat[oc0 + (to << 2) + 1];
    float b2 = bcat[oc0 + (to << 2) + 2];
    float b3 = bcat[oc0 + (to << 2) + 3];
    u16* dst = (og == 0) ? Qb : Kb;
#pragma unroll
    for (int i = 0; i < 4; ++i) {
        int n = n0 + (tn << 2) + i;
        ushort4 h;
        h.x = f2b(acc[i][0] + b0); h.y = f2b(acc[i][1] + b1);
        h.z = f2b(acc[i][2] + b2); h.w = f2b(acc[i][3] + b3);
        *(ushort4*)(dst + ((size_t)b * N_ + n) * 64 + (to << 2)) = h;
    }
}

// ---------------- kernel 3: MFMA single-pass attention + fused vw epilogue --------
// grid (64, 8) remapped XCD-bijectively, 512 threads (8 waves), 2 blocks/CU.
// Block: i-rows [i0, i0+64). Wave w: p_compute tile (rt=w&3 -> 16 i-rows,
// h2=w>>2 -> 64-j half of the 128-j tile); PV/epilogue c-slice [64w, 64w+64).
// K LDS is linear [128][64]u16 with 16B-granule XOR swizzle:
//   LDS[row*128 + (c ^ ((row&7)<<4))] = K[row][c]  (c = byte col, mult of 16)
// staged by global_load_lds with inverse-swizzled per-lane global source.
// LDS layout (byte offsets):
#define KSA_OFF  0        // K buf A [128][64]u16  16384 B (swizzled)
#define KSB_OFF  16384    // K buf B [128][64]u16  16384 B
#define PSA_OFF  32768    // P buf A [64][136]u16  17408 B
#define PSB_OFF  50176    // P buf B [64][136]u16  17408 B
#define YS_OFF   0        // epilogue ys [64][520]u16  66560 B (overlays KS/Ps)
#define LP_OFF   67584    // lpart [64][2] float      512 B
#define SMEM3    68096

#define SHIFT_C 20.0f     // softmax constant shift (overflow guard; result-invariant)

__global__ __launch_bounds__(512, 4) void attn_mfma(
        const u16* __restrict__ Qb, const u16* __restrict__ Kb,
        const u16* __restrict__ xbfw, const void* __restrict__ xin,
        const int* __restrict__ flagp,
        const u16* __restrict__ vwb, const float* __restrict__ vbf,
        const float* __restrict__ gf, void* __restrict__ outv) {
    __shared__ __align__(16) char smem[SMEM3];
    char* KsA = smem + KSA_OFF;
    char* KsB = smem + KSB_OFF;
    u16* PsA = (u16*)(smem + PSA_OFF);
    u16* PsB = (u16*)(smem + PSB_OFF);
    u16* ys  = (u16*)(smem + YS_OFF);
    float* lpart = (float*)(smem + LP_OFF);

    const u16*   xb = (const u16*)xin;
    const float* xf = (const float*)xin;
    const int fl = *flagp;
    const u16* xb16 = fl ? (const u16*)xin : xbfw;   // bf16 view of x

    const int t = threadIdx.x;
    const int wv = t >> 6;
    const int lane = t & 63;
    const int L = lane & 15;
    const int q = lane >> 4;
    const int rt = wv & 3;            // i-subtile
    const int h2 = wv >> 2;           // j-half (64-wide) of the 128-j tile

    // XCD-bijective remap: batch b pinned to XCD b (512 blocks, 512%8==0).
    const int gid  = blockIdx.y * 64 + blockIdx.x;
    const int ngid = (gid & 7) * 64 + (gid >> 3);
    const int b  = ngid >> 6;
    const int i0 = (ngid & 63) * 64;

    // Q fragments for this wave's 16 S-rows (i = i0 + 16rt + L)
    const u16* qp = Qb + ((size_t)b * N_ + i0 + 16 * rt + L) * 64;
    bf16x8 qf0 = *(const bf16x8*)(qp + 8 * q);
    bf16x8 qf1 = *(const bf16x8*)(qp + 32 + 8 * q);

    // per-lane partial row sums of exp(S - SHIFT_C); lane row i = 16rt+4q+r
    float lsum[4];
#pragma unroll
    for (int r = 0; r < 4; ++r) lsum[r] = 0.f;

    // acc[mt][nt]: y[c = 64wv+16mt+4q+r][i = 16nt+L]
    f32x4 acc[4][4];
#pragma unroll
    for (int a = 0; a < 4; ++a)
#pragma unroll
        for (int nb = 0; nb < 4; ++nb) acc[a][nb] = (f32x4){0.f, 0.f, 0.f, 0.f};

    // K staging (global_load_lds): wave w stages rows 16w..16w+15 (2 x 1KB).
    // lane l covers LDS linear off 16*l; src col inverse-swizzled.
    const int lane8 = lane >> 3;                       // 0..7
    const int kofs = (16 * wv + lane8) * 128 + ((((lane & 7) ^ lane8)) << 4);
    const char* ksrc0 = (const char*)Kb + ((size_t)b * N_) * 128 + kofs;
    char* kdstA = KsA + wv * 2048;
    char* kdstB = KsB + wv * 2048;
    // K read offsets (swizzled): row = 64h2+16h+L -> row&7 = L&7
    const int swzL = (L & 7) << 4;
    const int krd0 = L * 128 + ((16 * q) ^ swzL);
    const int krd1 = L * 128 + ((64 + 16 * q) ^ swzL);

    const u16* xrow = xb16 + ((size_t)(b * C_ + 64 * wv + L)) * N_ + 8 * q;

    auto stageK = [&](int jt) {   // stage K tile jt -> Ks[jt&1] (async)
        char* kd = (jt & 1) ? kdstB : kdstA;
        const char* gs = ksrc0 + (size_t)jt * 16384;
        glds16(gs, kd);
        glds16(gs + 1024, kd + 1024);
    };

    // p_compute in h-PAIRS: sv[2] live, exp issued early.
    auto p_compute = [&](int jt) {
        const char* kcur = (jt & 1) ? KsB : KsA;
        u16* psw = (jt & 1) ? PsB : PsA;
#pragma unroll
        for (int hp = 0; hp < 2; ++hp) {
            f32x4 sv[2];
#pragma unroll
            for (int hh = 0; hh < 2; ++hh) {
                int h = hp * 2 + hh;
                const char* kr = kcur + (64 * h2 + 16 * h) * 128;
                bf16x8 k0 = *(const bf16x8*)(kr + krd0);
                bf16x8 k1 = *(const bf16x8*)(kr + krd1);
                f32x4 z = {0.f, 0.f, 0.f, 0.f};
                z = __builtin_amdgcn_mfma_f32_16x16x32_bf16(qf0, k0, z, 0, 0, 0);
                z = __builtin_amdgcn_mfma_f32_16x16x32_bf16(qf1, k1, z, 0, 0, 0);
                sv[hh] = z;
            }
#pragma unroll
            for (int hh = 0; hh < 2; ++hh) {
                int h = hp * 2 + hh;
#pragma unroll
                for (int r = 0; r < 4; ++r) {
                    float p = __expf(sv[hh][r] - SHIFT_C);   // unnormalized
                    lsum[r] += p;
                    psw[(16 * rt + 4 * q + r) * 136 + 64 * h2 + 16 * h + L] = f2b(p);
                }
            }
        }
    };

    // pv_step with ks=0 af batch passed as 4 NAMED values (hoisted pre-p_compute).
    auto pv_step = [&](int jtp, bf16x8 ha0, bf16x8 ha1, bf16x8 ha2, bf16x8 ha3) {
        const u16* psr = (jtp & 1) ? PsB : PsA;
        const int j0pv = jtp << 7;
#pragma unroll
        for (int ks = 0; ks < 4; ++ks) {
            bf16x8 af0v, af1v, af2v, af3v;
            if (ks == 0) {
                af0v = ha0; af1v = ha1; af2v = ha2; af3v = ha3;
            } else {
                af0v = *(const bf16x8*)(xrow + (size_t)(0)  * N_ + j0pv + 32 * ks);
                af1v = *(const bf16x8*)(xrow + (size_t)(16) * N_ + j0pv + 32 * ks);
                af2v = *(const bf16x8*)(xrow + (size_t)(32) * N_ + j0pv + 32 * ks);
                af3v = *(const bf16x8*)(xrow + (size_t)(48) * N_ + j0pv + 32 * ks);
            }
            __builtin_amdgcn_s_setprio(1);
#pragma unroll
            for (int nt = 0; nt < 4; ++nt) {
                bf16x8 pb = *(const bf16x8*)(psr + (16 * nt + L) * 136 + 32 * ks + 8 * q);
                acc[0][nt] = __builtin_amdgcn_mfma_f32_16x16x32_bf16(
                    af0v, pb, acc[0][nt], 0, 0, 0);
                acc[1][nt] = __builtin_amdgcn_mfma_f32_16x16x32_bf16(
                    af1v, pb, acc[1][nt], 0, 0, 0);
                acc[2][nt] = __builtin_amdgcn_mfma_f32_16x16x32_bf16(
                    af2v, pb, acc[2][nt], 0, 0, 0);
                acc[3][nt] = __builtin_amdgcn_mfma_f32_16x16x32_bf16(
                    af3v, pb, acc[3][nt], 0, 0, 0);
            }
            __builtin_amdgcn_s_setprio(0);
        }
    };

    // prologue: stage K0, K1 async; barrier drains both.
    stageK(0);
    stageK(1);
    __syncthreads();
    p_compute(0);

    for (int jt = 1; jt < 32; ++jt) {
        __syncthreads();   // all waves done p_compute(jt-1) & pv_step(jt-2)
        // hoisted ks=0 af batch FIRST (so PV's wait is vmcnt(2), not vmcnt(0))
        const int j0h = (jt - 1) << 7;
        bf16x8 ha0 = *(const bf16x8*)(xrow + (size_t)(0)  * N_ + j0h);
        bf16x8 ha1 = *(const bf16x8*)(xrow + (size_t)(16) * N_ + j0h);
        bf16x8 ha2 = *(const bf16x8*)(xrow + (size_t)(32) * N_ + j0h);
        bf16x8 ha3 = *(const bf16x8*)(xrow + (size_t)(48) * N_ + j0h);
        if (jt < 31) stageK(jt + 1);   // async K DMA issued AFTER ha loads
        p_compute(jt);
        pv_step(jt - 1, ha0, ha1, ha2, ha3);
    }
    {   // flush the pipelined tile
        const int j0h = 31 << 7;
        bf16x8 ha0 = *(const bf16x8*)(xrow + (size_t)(0)  * N_ + j0h);
        bf16x8 ha1 = *(const bf16x8*)(xrow + (size_t)(16) * N_ + j0h);
        bf16x8 ha2 = *(const bf16x8*)(xrow + (size_t)(32) * N_ + j0h);
        bf16x8 ha3 = *(const bf16x8*)(xrow + (size_t)(48) * N_ + j0h);
        __syncthreads();   // P(31) visibility across waves
        pv_step(31, ha0, ha1, ha2, ha3);
    }

    // ---- finalize l: reduce own-row partials over L lanes, combine j-halves -------
#pragma unroll
    for (int r = 0; r < 4; ++r) {
#pragma unroll
        for (int off = 8; off > 0; off >>= 1)
            lsum[r] += __shfl_xor(lsum[r], off, 64);
    }
    if (L == 0) {
#pragma unroll
        for (int r = 0; r < 4; ++r)
            lpart[(16 * rt + 4 * q + r) * 2 + h2] = lsum[r];
    }
    __syncthreads();   // lpart visible; all Ps/Ks reads done (ys overlay safe)

    float fi[4];
#pragma unroll
    for (int nt = 0; nt < 4; ++nt) {
        int i = 16 * nt + L;
        fi[nt] = 1.0f / (lpart[i * 2] + lpart[i * 2 + 1]);
    }

    // ---- fused epilogue: z = vw @ y, out = gamma*(z+vb) + x ----
    // Write y (scaled by 1/l) once to ys[i][c], then barrier-free kc-GEMM.
#pragma unroll
    for (int mt = 0; mt < 4; ++mt)
#pragma unroll
        for (int nt = 0; nt < 4; ++nt) {
            ushort4 h;
            h.x = f2b(acc[mt][nt][0] * fi[nt]); h.y = f2b(acc[mt][nt][1] * fi[nt]);
            h.z = f2b(acc[mt][nt][2] * fi[nt]); h.w = f2b(acc[mt][nt][3] * fi[nt]);
            *(ushort4*)(ys + (16 * nt + L) * 520 + 64 * wv + 16 * mt + 4 * q) = h;
        }
    __syncthreads();

    const float gma = gf[0];
    f32x4 z[4][4];
#pragma unroll
    for (int a = 0; a < 4; ++a)
#pragma unroll
        for (int nb = 0; nb < 4; ++nb) z[a][nb] = (f32x4){0.f, 0.f, 0.f, 0.f};

#pragma unroll 1
    for (int kc = 0; kc < 8; ++kc) {
#pragma unroll
        for (int nn = 0; nn < 4; ++nn) {
            const u16* yr = ys + (16 * nn + L) * 520 + kc * 64;
            bf16x8 yb0 = *(const bf16x8*)(yr + 8 * q);
            bf16x8 yb1 = *(const bf16x8*)(yr + 32 + 8 * q);
#pragma unroll
            for (int mtp = 0; mtp < 4; ++mtp) {
                int crow = 64 * wv + 16 * mtp + L;
                const u16* wp = vwb + (size_t)crow * C_ + kc * 64;
                bf16x8 a0 = *(const bf16x8*)(wp + 8 * q);
                bf16x8 a1 = *(const bf16x8*)(wp + 32 + 8 * q);
                z[mtp][nn] = __builtin_amdgcn_mfma_f32_16x16x32_bf16(
                    a0, yb0, z[mtp][nn], 0, 0, 0);
                z[mtp][nn] = __builtin_amdgcn_mfma_f32_16x16x32_bf16(
                    a1, yb1, z[mtp][nn], 0, 0, 0);
            }
        }
    }
    // store
#pragma unroll
    for (int mtp = 0; mtp < 4; ++mtp)
#pragma unroll
        for (int nn = 0; nn < 4; ++nn)
#pragma unroll
            for (int r = 0; r < 4; ++r) {
                int cp = 64 * wv + 16 * mtp + 4 * q + r;
                int ii = i0 + 16 * nn + L;
                size_t oi = ((size_t)(b * C_ + cp)) * N_ + ii;
                float val = gma * (z[mtp][nn][r] + vbf[cp]);
                if (fl) ((u16*)outv)[oi] = f2b(val + b2f(xb[oi]));
                else    ((float*)outv)[oi] = val + xf[oi];
            }
}

extern "C" void kernel_launch(void* const* d_in, const int* in_sizes, int n_in,
                              void* d_out, int out_size, void* d_ws, size_t ws_size,
                              hipStream_t stream) {
    const void* x  = d_in[0];
    const void* qw = d_in[1];
    const void* qb = d_in[2];
    const void* kw = d_in[3];
    const void* kb = d_in[4];
    const void* vw = d_in[5];
    const void* vb = d_in[6];
    const void* gm = d_in[7];

    char* ws = (char*)d_ws;
    int*   flag = (int*)(ws + 0);
    float* gf   = (float*)(ws + 16);
    float* bcat = (float*)(ws + 32);
    float* vbf  = (float*)(ws + 544);
    float* wt   = (float*)(ws + 2592);
    u16*   Qb   = (u16*)(ws + 264736);
    u16*   Kb   = (u16*)(ws + 4459040);
    u16*   vwb  = (u16*)(ws + 8653344);
    u16*   xbf  = (u16*)(ws + 9177632);   // total ws use: 42,732,064 B

    detect_dtype<<<dim3(1), dim3(256), 0, stream>>>((const u16*)x, flag);
    prep_params<<<dim3(256), dim3(256), 0, stream>>>(
        qw, qb, kw, kb, vb, gm, vw, flag, wt, bcat, vbf, gf, vwb);
    proj_qk<<<dim3(2, 64, 8), dim3(256), 0, stream>>>(x, flag, wt, bcat, Qb, Kb, xbf);
    attn_mfma<<<dim3(64, 8), dim3(512), 0, stream>>>(
        Qb, Kb, xbf, x, flag, vwb, vbf, gf, d_out);
}

// Round 13
// 392.220 us; speedup vs baseline: 1.5069x; 1.2568x over previous
//
#include <hip/hip_runtime.h>
#include <stdint.h>

// PAM_Module: B=8, C=512, H=W=64 -> N=4096, O=64. Dtype auto-detected (bf16 vs fp32).
// out = gamma * (vw @ (xf @ att^T) + vb) + x   (softmax rows sum to 1 => vb passes through)
// MFMA pipeline:
//   K0 detect, K1 prep (wt/bcat/vbf/gf fp32 + vw->bf16 vwb),
//   K2 proj -> Qb,Kb bf16 [b][n][64] (fp32 path also writes xbf; bf16 aliases x),
//   K3 attn_mfma: single-pass shifted-exp softmax + PV + fused vw-GEMM epilogue.
//
// R13 = R12 with the swizzle-read fix. R12 produced NaN because
//   krd1 = L*128 + (64 + ((16q)^swzL))   [WRONG: +64 after XOR -> offsets to 176,
//   crosses rows; row 127 reads 48B past the K buffer -> uninit LDS -> NaN]
// must be
//   krd1 = L*128 + ((64 + 16q) ^ swzL)   [XOR stays within the 128-B row]
// (R11's form; transcription slip in the retile.)
//
// R12 theory (unchanged, now actually tested): the x A-fragment GATHER is the
// limiter (16-row gather per bf16x8 load). Tall-i retile c32 x i128 per wave
// (16 waves, 1024 thr, i-block 128, grid 256 = 1/CU):
//   - af load feeds 8 MFMAs (2x cover), 8 af loads/wave/iter (2x fewer),
//     32 blocks/batch (2x less x re-read). Same 128-reg cap, 16 waves/CU.
//   - j-tile 128, K via global_load_lds + XOR swizzle, depth-2 P/PV pipe.
//   - epilogue: acc packed to bf16 regs, then 2 x i64-half ys GEMM.
// ws: flag@0 gf@16 bcat@32 vbf@544 wt@2592 Qb@264736 Kb@4459040 vwb@8653344
//     xbf@9177632  (total 42,732,064 B)

#define B_ 8
#define C_ 512
#define N_ 4096

typedef unsigned short u16;
typedef unsigned int u32;
typedef __attribute__((ext_vector_type(8))) short bf16x8;
typedef __attribute__((ext_vector_type(4))) float f32x4;

static __device__ __forceinline__ float b2f(u16 u) {
    return __uint_as_float(((u32)u) << 16);
}
static __device__ __forceinline__ u16 f2b(float f) {
    u32 u = __float_as_uint(f);
    u = u + 0x7fffu + ((u >> 16) & 1u);   // RNE
    return (u16)(u >> 16);
}
static __device__ __forceinline__ float ldf(const void* p, size_t i, int fl) {
    return fl ? b2f(((const u16*)p)[i]) : ((const float*)p)[i];
}
static __device__ __forceinline__ void glds16(const void* g, void* l) {
    __builtin_amdgcn_global_load_lds(
        (const __attribute__((address_space(1))) unsigned int*)g,
        (__attribute__((address_space(3))) unsigned int*)l, 16, 0, 0);
}

// ---------------- kernel 0: dtype detector ----------------------------------------
__global__ void detect_dtype(const u16* __restrict__ x, int* __restrict__ flag) {
    __shared__ int cnt[256];
    int t = threadIdx.x;
    int c = 0;
    for (int i = t; i < 4096; i += 256) {
        int e = (x[i] >> 7) & 0xFF;
        if (e >= 95 && e <= 140) c++;
    }
    cnt[t] = c;
    __syncthreads();
    for (int s = 128; s > 0; s >>= 1) {
        if (t < s) cnt[t] += cnt[t + s];
        __syncthreads();
    }
    if (t == 0) *flag = (cnt[0] >= 3686) ? 1 : 0;   // 1 = bf16, 0 = fp32
}

// ---------------- kernel 1: params -> fp32 ws, vw -> bf16 --------------------------
__global__ void prep_params(const void* __restrict__ qw, const void* __restrict__ qb,
                            const void* __restrict__ kw, const void* __restrict__ kb,
                            const void* __restrict__ vb, const void* __restrict__ gm,
                            const void* __restrict__ vw, const int* __restrict__ flagp,
                            float* __restrict__ wt, float* __restrict__ bcat,
                            float* __restrict__ vbf, float* __restrict__ gf,
                            u16* __restrict__ vwb) {
    int fl = *flagp;
    int gid = blockIdx.x * 256 + threadIdx.x;   // grid 256*256 = 65536
    if (gid < C_ * 128) {
        int c = gid >> 7, o = gid & 127;
        wt[c * 128 + o] = (o < 64) ? ldf(qw, (size_t)o * C_ + c, fl)
                                   : ldf(kw, (size_t)(o - 64) * C_ + c, fl);
    }
    if (gid < 128) bcat[gid] = (gid < 64) ? ldf(qb, gid, fl) : ldf(kb, gid - 64, fl);
    if (gid < C_) vbf[gid] = ldf(vb, gid, fl);
    if (gid == 0) gf[0] = ldf(gm, 0, fl);
    {   // vw -> bf16: 65536 threads x 4 elems = 262144 = C*C
        int v0 = gid * 4;
        ushort4 h;
        h.x = f2b(ldf(vw, v0 + 0, fl));
        h.y = f2b(ldf(vw, v0 + 1, fl));
        h.z = f2b(ldf(vw, v0 + 2, fl));
        h.w = f2b(ldf(vw, v0 + 3, fl));
        *(ushort4*)(vwb + v0) = h;
    }
}

// ---------------- kernel 2: Q/K projection -> bf16, grid (2, 64, 8) ---------------
// fp32 input: og==0 blocks also emit x as bf16 into xbf (fused xconv).
__global__ __launch_bounds__(256) void proj_qk(
        const void* __restrict__ xin, const int* __restrict__ flagp,
        const float* __restrict__ wt, const float* __restrict__ bcat,
        u16* __restrict__ Qb, u16* __restrict__ Kb, u16* __restrict__ xbf) {
    __shared__ __align__(16) char smem[32768];
    float* xs  = (float*)smem;            // [64][64]
    float* wsh = (float*)(smem + 16384);  // [64][64]
    const u16*   xb = (const u16*)xin;
    const float* xf = (const float*)xin;
    int fl = *flagp;

    int t = threadIdx.x;
    int og = blockIdx.x;
    int n0 = blockIdx.y * 64;
    int b  = blockIdx.z;
    int oc0 = og * 64;
    int tn = t & 15, to = t >> 4;

    float acc[4][4];
#pragma unroll
    for (int i = 0; i < 4; ++i)
#pragma unroll
        for (int j = 0; j < 4; ++j) acc[i][j] = 0.f;

    for (int c0 = 0; c0 < C_; c0 += 64) {
        __syncthreads();
        if (fl) {
#pragma unroll
            for (int rep = 0; rep < 4; ++rep) {
                int idx4 = rep * 256 + t;
                int cc = idx4 >> 4;
                int nn4 = (idx4 & 15) << 2;
                ushort4 uv = *(const ushort4*)(xb + ((size_t)(b * C_ + c0 + cc)) * N_ + n0 + nn4);
                float4 f;
                f.x = b2f(uv.x); f.y = b2f(uv.y); f.z = b2f(uv.z); f.w = b2f(uv.w);
                *(float4*)(xs + cc * 64 + nn4) = f;
            }
        } else {
#pragma unroll
            for (int rep = 0; rep < 4; ++rep) {
                int idx4 = rep * 256 + t;
                int cc = idx4 >> 4;
                int nn4 = (idx4 & 15) << 2;
                float4 v = *(const float4*)(xf + ((size_t)(b * C_ + c0 + cc)) * N_ + n0 + nn4);
                *(float4*)(xs + cc * 64 + nn4) = v;
                if (og == 0) {   // fused x -> bf16 (each (b,c,n) written exactly once)
                    ushort4 h;
                    h.x = f2b(v.x); h.y = f2b(v.y); h.z = f2b(v.z); h.w = f2b(v.w);
                    *(ushort4*)(xbf + ((size_t)(b * C_ + c0 + cc)) * N_ + n0 + nn4) = h;
                }
            }
        }
#pragma unroll
        for (int rep = 0; rep < 4; ++rep) {
            int idx4 = rep * 256 + t;
            int cc = idx4 >> 4;
            int oo4 = (idx4 & 15) << 2;
            *(float4*)(wsh + cc * 64 + oo4) =
                *(const float4*)(wt + (size_t)(c0 + cc) * 128 + oc0 + oo4);
        }
        __syncthreads();
#pragma unroll 8
        for (int cc = 0; cc < 64; ++cc) {
            float4 xa = *(const float4*)(xs + cc * 64 + (tn << 2));
            float4 wa = *(const float4*)(wsh + cc * 64 + (to << 2));
            acc[0][0] += xa.x * wa.x; acc[0][1] += xa.x * wa.y;
            acc[0][2] += xa.x * wa.z; acc[0][3] += xa.x * wa.w;
            acc[1][0] += xa.y * wa.x; acc[1][1] += xa.y * wa.y;
            acc[1][2] += xa.y * wa.z; acc[1][3] += xa.y * wa.w;
            acc[2][0] += xa.z * wa.x; acc[2][1] += xa.z * wa.y;
            acc[2][2] += xa.z * wa.z; acc[2][3] += xa.z * wa.w;
            acc[3][0] += xa.w * wa.x; acc[3][1] += xa.w * wa.y;
            acc[3][2] += xa.w * wa.z; acc[3][3] += xa.w * wa.w;
        }
    }

    float b0 = bcat[oc0 + (to << 2) + 0];
    float b1 = bcat[oc0 + (to << 2) + 1];
    float b2 = bcat[oc0 + (to << 2) + 2];
    float b3 = bcat[oc0 + (to << 2) + 3];
    u16* dst = (og == 0) ? Qb : Kb;
#pragma unroll
    for (int i = 0; i < 4; ++i) {
        int n = n0 + (tn << 2) + i;
        ushort4 h;
        h.x = f2b(acc[i][0] + b0); h.y = f2b(acc[i][1] + b1);
        h.z = f2b(acc[i][2] + b2); h.w = f2b(acc[i][3] + b3);
        *(ushort4*)(dst + ((size_t)b * N_ + n) * 64 + (to << 2)) = h;
    }
}

// ---------------- kernel 3: MFMA single-pass attention + fused vw epilogue --------
// grid (32, 8) remapped XCD-bijectively, 1024 threads (16 waves), 1 block/CU.
// Block: i-rows [i0, i0+128). Wave w: p_compute tile (rt=w&7 -> 16 i-rows,
// h2=w>>3 -> 64-j half of the 128-j tile); PV/epilogue c-slice [32w, 32w+32).
// K LDS linear [128][64]u16, 16B-granule XOR swizzle (rule #21):
//   LDS[row*128 + (c ^ ((row&7)<<4))] = K[row][c]; staged via global_load_lds
//   with inverse-swizzled per-lane global source (1 glds16 per wave = 8 rows).
// LDS layout (byte offsets):
#define KSA_OFF  0        // K buf A [128][64]u16   16384 B (swizzled)
#define KSB_OFF  16384    // K buf B [128][64]u16   16384 B
#define PSA_OFF  32768    // P buf A [128][136]u16  34816 B
#define PSB_OFF  67584    // P buf B [128][136]u16  34816 B
#define LP_OFF   102400   // lpart [128][2] float    1024 B
#define YS_OFF   0        // epilogue ys [64][520]u16  66560 B (overlays Ks/PsA)
#define SMEM3    103424

#define SHIFT_C 20.0f     // softmax constant shift (overflow guard; result-invariant)

__global__ __launch_bounds__(1024, 4) void attn_mfma(
        const u16* __restrict__ Qb, const u16* __restrict__ Kb,
        const u16* __restrict__ xbfw, const void* __restrict__ xin,
        const int* __restrict__ flagp,
        const u16* __restrict__ vwb, const float* __restrict__ vbf,
        const float* __restrict__ gf, void* __restrict__ outv) {
    __shared__ __align__(16) char smem[SMEM3];
    char* KsA = smem + KSA_OFF;
    char* KsB = smem + KSB_OFF;
    u16* PsA = (u16*)(smem + PSA_OFF);
    u16* PsB = (u16*)(smem + PSB_OFF);
    u16* ys  = (u16*)(smem + YS_OFF);
    float* lpart = (float*)(smem + LP_OFF);

    const u16*   xb = (const u16*)xin;
    const float* xf = (const float*)xin;
    const int fl = *flagp;
    const u16* xb16 = fl ? (const u16*)xin : xbfw;   // bf16 view of x

    const int t = threadIdx.x;
    const int wv = t >> 6;            // 0..15
    const int lane = t & 63;
    const int L = lane & 15;
    const int q = lane >> 4;
    const int rt = wv & 7;            // i-subtile (16 rows each, 128 total)
    const int h2 = wv >> 3;           // j-half (64-wide) of the 128-j tile

    // XCD-bijective remap: batch b pinned to XCD b (256 blocks, 256%8==0).
    const int gid  = blockIdx.y * 32 + blockIdx.x;
    const int ngid = (gid & 7) * 32 + (gid >> 3);
    const int b  = ngid >> 5;
    const int i0 = (ngid & 31) * 128;

    // Q fragments for this wave's 16 S-rows (i = i0 + 16rt + L)
    const u16* qp = Qb + ((size_t)b * N_ + i0 + 16 * rt + L) * 64;
    bf16x8 qf0 = *(const bf16x8*)(qp + 8 * q);
    bf16x8 qf1 = *(const bf16x8*)(qp + 32 + 8 * q);

    // per-lane partial row sums of exp(S - SHIFT_C); lane row i = 16rt+4q+r
    float lsum[4];
#pragma unroll
    for (int r = 0; r < 4; ++r) lsum[r] = 0.f;

    // acc[mt][nt]: y[c = 32wv+16mt+4q+r][i = 16nt+L]  (2 c-tiles x 8 i-tiles)
    f32x4 acc[2][8];
#pragma unroll
    for (int a = 0; a < 2; ++a)
#pragma unroll
        for (int nb = 0; nb < 8; ++nb) acc[a][nb] = (f32x4){0.f, 0.f, 0.f, 0.f};

    // K staging: wave w stages rows 8w..8w+7 with ONE glds16 (64 lanes x 16B = 1KB).
    const int lane8 = lane >> 3;      // 0..7 = row within wave's 8-row slab
    const int kofs = (8 * wv + lane8) * 128 + ((((lane & 7) ^ lane8)) << 4);
    const char* ksrc0 = (const char*)Kb + ((size_t)b * N_) * 128 + kofs;
    char* kdstA = KsA + wv * 1024;
    char* kdstB = KsB + wv * 1024;
    // K read offsets (swizzled): row = 64h2+16h+L -> row&7 = L&7.
    // XOR must wrap WITHIN the 128-B row: apply to the full column (R12 bug:
    // adding 64 after the XOR crossed rows / ran 48B past the buffer -> NaN).
    const int swzL = (L & 7) << 4;
    const int krd0 = L * 128 + ((16 * q) ^ swzL);
    const int krd1 = L * 128 + ((64 + 16 * q) ^ swzL);

    const u16* xrow = xb16 + ((size_t)(b * C_ + 32 * wv + L)) * N_ + 8 * q;

    auto stageK = [&](int jt) {   // stage K tile jt -> Ks[jt&1] (async, 0 regs)
        glds16(ksrc0 + (size_t)jt * 16384, (jt & 1) ? kdstB : kdstA);
    };

    // p_compute in h-PAIRS: sv[2] live, exp issued early.
    auto p_compute = [&](int jt) {
        const char* kcur = (jt & 1) ? KsB : KsA;
        u16* psw = (jt & 1) ? PsB : PsA;
#pragma unroll
        for (int hp = 0; hp < 2; ++hp) {
            f32x4 sv[2];
#pragma unroll
            for (int hh = 0; hh < 2; ++hh) {
                int h = hp * 2 + hh;
                const char* kr = kcur + (64 * h2 + 16 * h) * 128;
                bf16x8 k0 = *(const bf16x8*)(kr + krd0);
                bf16x8 k1 = *(const bf16x8*)(kr + krd1);
                f32x4 z = {0.f, 0.f, 0.f, 0.f};
                z = __builtin_amdgcn_mfma_f32_16x16x32_bf16(qf0, k0, z, 0, 0, 0);
                z = __builtin_amdgcn_mfma_f32_16x16x32_bf16(qf1, k1, z, 0, 0, 0);
                sv[hh] = z;
            }
#pragma unroll
            for (int hh = 0; hh < 2; ++hh) {
                int h = hp * 2 + hh;
#pragma unroll
                for (int r = 0; r < 4; ++r) {
                    float p = __expf(sv[hh][r] - SHIFT_C);   // unnormalized
                    lsum[r] += p;
                    psw[(16 * rt + 4 * q + r) * 136 + 64 * h2 + 16 * h + L] = f2b(p);
                }
            }
        }
    };

    // pv: 2 af loads per ks feed 16 MFMAs (2x the cover of the old c64 tile).
    auto pv_step = [&](int jtp) {
        const u16* psr = (jtp & 1) ? PsB : PsA;
        const int j0pv = jtp << 7;
#pragma unroll
        for (int ks = 0; ks < 4; ++ks) {
            bf16x8 af0v = *(const bf16x8*)(xrow + (size_t)(0)  * N_ + j0pv + 32 * ks);
            bf16x8 af1v = *(const bf16x8*)(xrow + (size_t)(16) * N_ + j0pv + 32 * ks);
            __builtin_amdgcn_s_setprio(1);
#pragma unroll
            for (int nt = 0; nt < 8; ++nt) {
                bf16x8 pb = *(const bf16x8*)(psr + (16 * nt + L) * 136 + 32 * ks + 8 * q);
                acc[0][nt] = __builtin_amdgcn_mfma_f32_16x16x32_bf16(
                    af0v, pb, acc[0][nt], 0, 0, 0);
                acc[1][nt] = __builtin_amdgcn_mfma_f32_16x16x32_bf16(
                    af1v, pb, acc[1][nt], 0, 0, 0);
            }
            __builtin_amdgcn_s_setprio(0);
        }
    };

    // prologue: stage K0, K1 async; barrier drains both.
    stageK(0);
    stageK(1);
    __syncthreads();
    p_compute(0);

    for (int jt = 1; jt < 32; ++jt) {
        __syncthreads();   // all waves done p_compute(jt-1) & pv_step(jt-2)
        if (jt < 31) stageK(jt + 1);   // async; covered by p_compute below
        p_compute(jt);
        pv_step(jt - 1);
    }
    __syncthreads();       // P(31) visibility across waves
    pv_step(31);

    // ---- finalize l: reduce own-row partials over L lanes, combine j-halves -------
#pragma unroll
    for (int r = 0; r < 4; ++r) {
#pragma unroll
        for (int off = 8; off > 0; off >>= 1)
            lsum[r] += __shfl_xor(lsum[r], off, 64);
    }
    if (L == 0) {
#pragma unroll
        for (int r = 0; r < 4; ++r)
            lpart[(16 * rt + 4 * q + r) * 2 + h2] = lsum[r];
    }
    __syncthreads();   // lpart visible; all Ps/Ks reads done (ys overlay safe)

    float fi[8];
#pragma unroll
    for (int nt = 0; nt < 8; ++nt) {
        int i = 16 * nt + L;
        fi[nt] = 1.0f / (lpart[i * 2] + lpart[i * 2 + 1]);
    }

    // pack acc -> bf16 (scaled by 1/l); frees the 64 acc AGPRs for the epilogue z.
    ushort4 pk[2][8];
#pragma unroll
    for (int mt = 0; mt < 2; ++mt)
#pragma unroll
        for (int nt = 0; nt < 8; ++nt) {
            ushort4 h;
            h.x = f2b(acc[mt][nt][0] * fi[nt]); h.y = f2b(acc[mt][nt][1] * fi[nt]);
            h.z = f2b(acc[mt][nt][2] * fi[nt]); h.w = f2b(acc[mt][nt][3] * fi[nt]);
            pk[mt][nt] = h;
        }

    // ---- fused epilogue: z = vw @ y, out = gamma*(z+vb) + x, two i64 halves -------
    const float gma = gf[0];
#pragma unroll
    for (int ih = 0; ih < 2; ++ih) {
        if (ih) __syncthreads();   // previous half's ys reads complete
#pragma unroll
        for (int mt = 0; mt < 2; ++mt)
#pragma unroll
            for (int nn = 0; nn < 4; ++nn)
                *(ushort4*)(ys + (16 * nn + L) * 520 + 32 * wv + 16 * mt + 4 * q) =
                    pk[mt][ih * 4 + nn];
        __syncthreads();

        f32x4 z[2][4];
#pragma unroll
        for (int a = 0; a < 2; ++a)
#pragma unroll
            for (int nb = 0; nb < 4; ++nb) z[a][nb] = (f32x4){0.f, 0.f, 0.f, 0.f};

#pragma unroll 1
        for (int kc = 0; kc < 8; ++kc) {
#pragma unroll
            for (int nn = 0; nn < 4; ++nn) {
                const u16* yr = ys + (16 * nn + L) * 520 + kc * 64;
                bf16x8 yb0 = *(const bf16x8*)(yr + 8 * q);
                bf16x8 yb1 = *(const bf16x8*)(yr + 32 + 8 * q);
#pragma unroll
                for (int mtp = 0; mtp < 2; ++mtp) {
                    int crow = 32 * wv + 16 * mtp + L;
                    const u16* wp = vwb + (size_t)crow * C_ + kc * 64;
                    bf16x8 a0 = *(const bf16x8*)(wp + 8 * q);
                    bf16x8 a1 = *(const bf16x8*)(wp + 32 + 8 * q);
                    z[mtp][nn] = __builtin_amdgcn_mfma_f32_16x16x32_bf16(
                        a0, yb0, z[mtp][nn], 0, 0, 0);
                    z[mtp][nn] = __builtin_amdgcn_mfma_f32_16x16x32_bf16(
                        a1, yb1, z[mtp][nn], 0, 0, 0);
                }
            }
        }
        // store this i-half
#pragma unroll
        for (int mtp = 0; mtp < 2; ++mtp)
#pragma unroll
            for (int nn = 0; nn < 4; ++nn)
#pragma unroll
                for (int r = 0; r < 4; ++r) {
                    int cp = 32 * wv + 16 * mtp + 4 * q + r;
                    int ii = i0 + ih * 64 + 16 * nn + L;
                    size_t oi = ((size_t)(b * C_ + cp)) * N_ + ii;
                    float val = gma * (z[mtp][nn][r] + vbf[cp]);
                    if (fl) ((u16*)outv)[oi] = f2b(val + b2f(xb[oi]));
                    else    ((float*)outv)[oi] = val + xf[oi];
                }
    }
}

extern "C" void kernel_launch(void* const* d_in, const int* in_sizes, int n_in,
                              void* d_out, int out_size, void* d_ws, size_t ws_size,
                              hipStream_t stream) {
    const void* x  = d_in[0];
    const void* qw = d_in[1];
    const void* qb = d_in[2];
    const void* kw = d_in[3];
    const void* kb = d_in[4];
    const void* vw = d_in[5];
    const void* vb = d_in[6];
    const void* gm = d_in[7];

    char* ws = (char*)d_ws;
    int*   flag = (int*)(ws + 0);
    float* gf   = (float*)(ws + 16);
    float* bcat = (float*)(ws + 32);
    float* vbf  = (float*)(ws + 544);
    float* wt   = (float*)(ws + 2592);
    u16*   Qb   = (u16*)(ws + 264736);
    u16*   Kb   = (u16*)(ws + 4459040);
    u16*   vwb  = (u16*)(ws + 8653344);
    u16*   xbf  = (u16*)(ws + 9177632);   // total ws use: 42,732,064 B

    detect_dtype<<<dim3(1), dim3(256), 0, stream>>>((const u16*)x, flag);
    prep_params<<<dim3(256), dim3(256), 0, stream>>>(
        qw, qb, kw, kb, vb, gm, vw, flag, wt, bcat, vbf, gf, vwb);
    proj_qk<<<dim3(2, 64, 8), dim3(256), 0, stream>>>(x, flag, wt, bcat, Qb, Kb, xbf);
    attn_mfma<<<dim3(32, 8), dim3(1024), 0, stream>>>(
        Qb, Kb, xbf, x, flag, vwb, vbf, gf, d_out);
}